// Round 8
// baseline (172.467 us; speedup 1.0000x reference)
//
#include <hip/hip_runtime.h>
#include <math.h>

#define BB 256
#define NN 512
#define DD 6
#define F_IN 62
#define HH 128
#define ND 7
#define TOTAL (BB*NN)   // 131072
#define OPB 640         // padded order slots per batch (512 + <=105 pad, 16-aligned buckets)
#define GPB 40          // 16-row groups per batch
#define TPB 10          // max 64-row tiles per batch

typedef __bf16 bf16x8 __attribute__((ext_vector_type(8)));
typedef float f32x4 __attribute__((ext_vector_type(4)));

__device__ __forceinline__ unsigned short f2bf(float f) {
    unsigned u = __builtin_bit_cast(unsigned, f);
    u = (u + 0x7FFFu + ((u >> 16) & 1u)) >> 16;
    return (unsigned short)u;
}
__device__ __forceinline__ float lo2f(unsigned x) { return __builtin_bit_cast(float, x << 16); }
__device__ __forceinline__ float hi2f(unsigned x) { return __builtin_bit_cast(float, x & 0xFFFF0000u); }

__device__ __forceinline__ uint4 pack8(const float* s) {
    uint4 r;
    r.x = (unsigned)f2bf(s[0]) | ((unsigned)f2bf(s[1]) << 16);
    r.y = (unsigned)f2bf(s[2]) | ((unsigned)f2bf(s[3]) << 16);
    r.z = (unsigned)f2bf(s[4]) | ((unsigned)f2bf(s[5]) << 16);
    r.w = (unsigned)f2bf(s[6]) | ((unsigned)f2bf(s[7]) << 16);
    return r;
}
__device__ __forceinline__ void unpack_add(float* s, uint4 q) {
    s[0] += lo2f(q.x); s[1] += hi2f(q.x); s[2] += lo2f(q.y); s[3] += hi2f(q.y);
    s[4] += lo2f(q.z); s[5] += hi2f(q.z); s[6] += lo2f(q.w); s[7] += hi2f(q.w);
}
__device__ __forceinline__ void unpack_max(float* s, uint4 q) {
    s[0] = fmaxf(s[0], lo2f(q.x)); s[1] = fmaxf(s[1], hi2f(q.x));
    s[2] = fmaxf(s[2], lo2f(q.y)); s[3] = fmaxf(s[3], hi2f(q.y));
    s[4] = fmaxf(s[4], lo2f(q.z)); s[5] = fmaxf(s[5], hi2f(q.z));
    s[6] = fmaxf(s[6], lo2f(q.w)); s[7] = fmaxf(s[7], hi2f(q.w));
}

// ---------------- per-batch counting sort by degree, buckets padded to 16 ----------------

__global__ __launch_bounds__(512) void k_sort16(const int* __restrict__ e,
                                                int* __restrict__ order,
                                                int* __restrict__ dgrp,
                                                int* __restrict__ ntiles) {
    __shared__ unsigned int scnt[ND];
    __shared__ unsigned int sbase[ND + 1];
    const int b = blockIdx.x;
    const int t = threadIdx.x;
    if (t < ND) scnt[t] = 0u;
    for (int i = t; i < OPB; i += 512) order[b * OPB + i] = -1;
    __syncthreads();
    int d = 0;
#pragma unroll
    for (int j = 0; j < DD; ++j) d += (e[(b * NN + t) * DD + j] >= 0) ? 1 : 0;
    unsigned rk = atomicAdd(&scnt[d], 1u);
    __syncthreads();
    if (t == 0) {
        unsigned acc = 0;
        for (int k = 0; k < ND; ++k) { sbase[k] = acc; acc += (scnt[k] + 15u) & ~15u; }
        sbase[ND] = acc;
        for (int k = 0; k < ND; ++k)
            for (unsigned g = sbase[k] >> 4; g < (sbase[k + 1] >> 4); ++g)
                dgrp[b * GPB + g] = k;
        for (unsigned g = acc >> 4; g < GPB; ++g) dgrp[b * GPB + g] = 0;
        ntiles[b] = (int)((acc + 63u) >> 6);
    }
    __syncthreads();
    order[b * OPB + sbase[d] + rk] = t;
}

// ---------------- prep: W [ND][F][HH] f32 -> WT [ND][HH][K] bf16 (K-contig, pad) ----------------

__global__ void k_prep_wt(const float* __restrict__ W, unsigned short* __restrict__ WT,
                          int F, int K) {
    int n = blockIdx.x;   // 0..127
    int d = blockIdx.y;   // 0..6
    for (int k = threadIdx.x; k < K; k += 64) {
        float v = (k < F) ? W[((size_t)d * F + k) * HH + n] : 0.f;
        WT[((size_t)d * HH + n) * K + k] = f2bf(v);
    }
}

// ---------------- gather1: S1[slot] = a[v] + sum(a[nbr]) in sorted order, bf16 [b][OPB][64] ----
// Pure streaming: no LDS, no barriers, one (slot, 8-col unit) per thread.

__global__ __launch_bounds__(512)
void k_gather1(const float* __restrict__ a, const int* __restrict__ e,
               const int* __restrict__ order, const int* __restrict__ ntiles,
               unsigned short* __restrict__ S1) {
    const int t = threadIdx.x;
    const int bi = blockIdx.x;
    const int x8 = bi & 7;
    const int j = bi >> 3;
    const int batch = x8 + 8 * (j / TPB);
    const int blk = j % TPB;                 // 64 slots = 1 tile per block
    if (blk >= ntiles[batch]) return;
    const int slot = blk * 64 + (t >> 3);
    const int kb = t & 7;
    const int v = order[batch * OPB + slot];
    if (v < 0) return;
    const int* ep = e + ((size_t)batch * NN + v) * DD;
    const float* base = a + (size_t)batch * NN * F_IN;
    float s[8] = {0.f, 0.f, 0.f, 0.f, 0.f, 0.f, 0.f, 0.f};
    {
        const float* r = base + (size_t)v * F_IN + kb * 8;
        float2 z0 = *(const float2*)(r);     s[0] += z0.x; s[1] += z0.y;
        float2 z1 = *(const float2*)(r + 2); s[2] += z1.x; s[3] += z1.y;
        float2 z2 = *(const float2*)(r + 4); s[4] += z2.x; s[5] += z2.y;
        if (kb < 7) { float2 z3 = *(const float2*)(r + 6); s[6] += z3.x; s[7] += z3.y; }
    }
#pragma unroll
    for (int jj = 0; jj < DD; ++jj) {
        int idx = ep[jj];
        if (idx >= 0) {
            const float* r = base + (size_t)idx * F_IN + kb * 8;
            float2 z0 = *(const float2*)(r);     s[0] += z0.x; s[1] += z0.y;
            float2 z1 = *(const float2*)(r + 2); s[2] += z1.x; s[3] += z1.y;
            float2 z2 = *(const float2*)(r + 4); s[4] += z2.x; s[5] += z2.y;
            if (kb < 7) { float2 z3 = *(const float2*)(r + 6); s[6] += z3.x; s[7] += z3.y; }
        }
    }
    *(uint4*)(S1 + ((size_t)batch * OPB + slot) * 64 + kb * 8) = pack8(s);
}

// ---------------- gather2: S2[slot] = p1[v] + sum(p1[nbr]) in sorted order ----------------
// S2 split: slots <512 -> S2m [b][512][128] (overlays dead h1), slots >=512 -> S2p [b][128][128].

__global__ __launch_bounds__(512)
void k_gather2(const unsigned short* __restrict__ P1, const int* __restrict__ e,
               const int* __restrict__ order, const int* __restrict__ ntiles,
               unsigned short* __restrict__ S2m, unsigned short* __restrict__ S2p) {
    constexpr int BPB2 = 20;                 // 32 slots per block
    const int t = threadIdx.x;
    const int bi = blockIdx.x;
    const int x8 = bi & 7;
    const int j = bi >> 3;
    const int batch = x8 + 8 * (j / BPB2);
    const int blk = j % BPB2;
    if ((blk >> 1) >= ntiles[batch]) return;
    const int slot = blk * 32 + (t >> 4);
    const int kb = t & 15;
    const int v = order[batch * OPB + slot];
    if (v < 0) return;
    const int* ep = e + ((size_t)batch * NN + v) * DD;
    const unsigned short* base = P1 + (size_t)batch * NN * HH + kb * 8;
    float s[8] = {0.f, 0.f, 0.f, 0.f, 0.f, 0.f, 0.f, 0.f};
    unpack_add(s, *(const uint4*)(base + (size_t)v * HH));
#pragma unroll
    for (int jj = 0; jj < DD; ++jj) {
        int idx = ep[jj];
        if (idx >= 0) unpack_add(s, *(const uint4*)(base + (size_t)idx * HH));
    }
    uint4 r = pack8(s);
    if (slot < 512) *(uint4*)(S2m + ((size_t)batch * 512 + slot) * HH + kb * 8) = r;
    else            *(uint4*)(S2p + ((size_t)batch * 128 + (slot - 512)) * HH + kb * 8) = r;
}

// ---------------- dense degree-pure GEMM: Y[v] = sigmoid(S[slot] @ W[deg] + b[deg]) ----------

template<int KB>   // 8 (K=64) or 16 (K=128)
__global__ __launch_bounds__(512, 4)
void k_gemm(const unsigned short* __restrict__ Sm, const unsigned short* __restrict__ Sp,
            const unsigned short* __restrict__ WT, const float* __restrict__ bias,
            const int* __restrict__ order, const int* __restrict__ dgrp,
            const int* __restrict__ ntiles, unsigned short* __restrict__ Y) {
    constexpr int K = KB * 8;
    constexpr int LOGKB = (KB == 16) ? 4 : 3;
    __shared__ unsigned short sP[64 * 128];
    __shared__ int vT[64];

    const int t = threadIdx.x;
    const int l = t & 63;
    const int w = t >> 6;

    const int bi = blockIdx.x;
    const int x8 = bi & 7;
    const int j = bi >> 3;
    const int batch = x8 + 8 * (j / TPB);
    const int tile = j % TPB;
    if (tile >= ntiles[batch]) return;

    if (t < 64) vT[t] = order[batch * OPB + tile * 64 + t];

    // contiguous coalesced tile load -> swizzled LDS
    for (int u = t; u < 64 * KB; u += 512) {
        const int n = u >> LOGKB;
        const int kb = u & (KB - 1);
        const int slot = tile * 64 + n;
        const unsigned short* src;
        if constexpr (KB == 16) {
            src = (slot < 512) ? Sm + ((size_t)batch * 512 + slot) * K + kb * 8
                               : Sp + ((size_t)batch * 128 + (slot - 512)) * K + kb * 8;
        } else {
            src = Sm + ((size_t)batch * OPB + slot) * K + kb * 8;
        }
        *(uint4*)&sP[(n * KB + (kb ^ (n & 7))) * 8] = *(const uint4*)src;
    }
    __syncthreads();

    // MFMA: wave w -> 16-row group mb = w>>1 (degree-pure), cols [col0, col0+64)
    const int lr = l & 15;
    const int lq = l >> 4;
    const int mb = w >> 1;
    const int col0 = (w & 1) * 64;
    const int d = dgrp[batch * GPB + tile * 4 + mb];
    const int nrow = mb * 16 + lr;

    bf16x8 af[K / 32];
#pragma unroll
    for (int kk = 0; kk < K / 32; ++kk)
        af[kk] = *(const bf16x8*)&sP[(nrow * KB + ((kk * 4 + lq) ^ (nrow & 7))) * 8];

    f32x4 acc[4];
#pragma unroll
    for (int fr = 0; fr < 4; ++fr) { f32x4 z = {0.f, 0.f, 0.f, 0.f}; acc[fr] = z; }
#pragma unroll
    for (int fr = 0; fr < 4; ++fr) {
        const unsigned short* wp = WT + ((size_t)d * HH + col0 + fr * 16 + lr) * K + lq * 8;
#pragma unroll
        for (int kk = 0; kk < K / 32; ++kk) {
            bf16x8 bfr = *(const bf16x8*)(wp + kk * 32);
            acc[fr] = __builtin_amdgcn_mfma_f32_16x16x32_bf16(af[kk], bfr, acc[fr], 0, 0, 0);
        }
    }

    __syncthreads();   // all A-frag reads done; reuse sP as [64][128] staging
#pragma unroll
    for (int fr = 0; fr < 4; ++fr) {
        const int col = col0 + fr * 16 + lr;
        const float bv = bias[d * HH + col];
#pragma unroll
        for (int r = 0; r < 4; ++r) {
            const int n = mb * 16 + lq * 4 + r;
            float z = 1.f / (1.f + __expf(-(acc[fr][r] + bv)));
            sP[n * HH + col] = f2bf(z);
        }
    }
    __syncthreads();
    for (int u = t; u < 1024; u += 512) {
        int n = u >> 4;
        int c8 = (u & 15) * 8;
        int v = vT[n];
        if (v >= 0) {
            uint4 p = *(const uint4*)&sP[n * HH + c8];
            *(uint4*)&Y[((size_t)batch * NN + v) * HH + c8] = p;
        }
    }
}

// ---------------- pool: P[v] = max(X[v], X[neighbors]) on bf16 rows ----------------

__global__ __launch_bounds__(256) void k_pool_bf(const unsigned short* __restrict__ X,
                                                 const int* __restrict__ e,
                                                 unsigned short* __restrict__ P) {
    const int t = threadIdx.x;
    const int bi = blockIdx.x;
    const int x8 = bi & 7;
    const int j = bi >> 3;
    const int batch = x8 + 8 * (j >> 5);
    const int sub = j & 31;
    const int u = batch * NN + sub * 16 + (t >> 4);
    const int c8 = (t & 15) * 8;
    const int nbase = u & ~(NN - 1);
    float m[8];
    {
        uint4 p = *(const uint4*)(X + (size_t)u * HH + c8);
        m[0] = lo2f(p.x); m[1] = hi2f(p.x); m[2] = lo2f(p.y); m[3] = hi2f(p.y);
        m[4] = lo2f(p.z); m[5] = hi2f(p.z); m[6] = lo2f(p.w); m[7] = hi2f(p.w);
    }
#pragma unroll
    for (int jj = 0; jj < DD; ++jj) {
        int idx = e[u * DD + jj];
        if (idx >= 0) unpack_max(m, *(const uint4*)(X + (size_t)(nbase + idx) * HH + c8));
    }
    *(uint4*)&P[(size_t)u * HH + c8] = pack8(m);
}

// ---------------- final: pool + partial sum (32 blocks/batch) ----------------

__global__ __launch_bounds__(256) void k_pool_sum_part(const unsigned short* __restrict__ X,
                                                       const int* __restrict__ e,
                                                       float* __restrict__ partial) {
    __shared__ float red[16][HH + 4];
    const int t = threadIdx.x;
    const int bi = blockIdx.x;
    const int x8 = bi & 7;
    const int j = bi >> 3;
    const int b = x8 + 8 * (j >> 5);
    const int chunk = j & 31;
    const int slot = t >> 4;
    const int c8 = (t & 15) * 8;

    const int u = b * NN + chunk * 16 + slot;
    float m[8];
    {
        uint4 p = *(const uint4*)(X + (size_t)u * HH + c8);
        m[0] = lo2f(p.x); m[1] = hi2f(p.x); m[2] = lo2f(p.y); m[3] = hi2f(p.y);
        m[4] = lo2f(p.z); m[5] = hi2f(p.z); m[6] = lo2f(p.w); m[7] = hi2f(p.w);
    }
#pragma unroll
    for (int jj = 0; jj < DD; ++jj) {
        int idx = e[u * DD + jj];
        if (idx >= 0) unpack_max(m, *(const uint4*)(X + (size_t)(b * NN + idx) * HH + c8));
    }
#pragma unroll
    for (int i = 0; i < 8; ++i) red[slot][c8 + i] = m[i];
    __syncthreads();
    if (t < HH) {
        float s = 0.f;
#pragma unroll
        for (int k = 0; k < 16; ++k) s += red[k][t];
        partial[((size_t)b * 32 + chunk) * HH + t] = s;
    }
}

// ---------------- final reduce: out[b][c] = sum of 32 partials (deterministic) ----------------

__global__ __launch_bounds__(256) void k_sum_final(const float* __restrict__ partial,
                                                   float* __restrict__ out) {
    int g = blockIdx.x * 256 + threadIdx.x;   // b*HH + c, 32768 total
    int b = g >> 7;
    int c = g & 127;
    float s = 0.f;
#pragma unroll
    for (int k = 0; k < 32; ++k) s += partial[((size_t)b * 32 + k) * HH + c];
    out[g] = s;
}

// ---------------- launcher ----------------
// ws overlays (lifetimes disjoint):
//   A [0,32M):   h1 (gemm1 out, pool1 in) -> S2m (gather2 out, gemm2 in)
//   B [32M,64M): S1 (gather1 out, gemm1 in) -> p1 (pool1 out, gather2 in) -> h2 (gemm2 out)
//   C [64M,72M): S2p pad rows -> partial
//   D [72M+):    WT0, WT1, order, dgrp, ntiles      (total ~76.5 MB)

extern "C" void kernel_launch(void* const* d_in, const int* in_sizes, int n_in,
                              void* d_out, int out_size, void* d_ws, size_t ws_size,
                              hipStream_t stream) {
    const float* a  = (const float*)d_in[0];
    const int*   e  = (const int*)d_in[1];
    const float* W0 = (const float*)d_in[2];
    const float* b0 = (const float*)d_in[3];
    const float* W1 = (const float*)d_in[4];
    const float* b1 = (const float*)d_in[5];
    float* out = (float*)d_out;

    char* ws = (char*)d_ws;
    const size_t MB32 = (size_t)TOTAL * HH * 2;                 // 33,554,432
    unsigned short* bufA = (unsigned short*)ws;
    unsigned short* bufB = (unsigned short*)(ws + MB32);
    unsigned short* S2p  = (unsigned short*)(ws + 2 * MB32);    // BB*128*HH bf16 = 8 MB
    float* partial = (float*)S2p;
    char* dp = ws + 2 * MB32 + (size_t)BB * 128 * HH * 2;
    unsigned short* WT0 = (unsigned short*)dp;
    unsigned short* WT1 = WT0 + (size_t)ND * HH * 64;
    int* order  = (int*)(WT1 + (size_t)ND * HH * 128);
    int* dgrp   = order + (size_t)BB * OPB;
    int* ntiles = dgrp + (size_t)BB * GPB;

    hipLaunchKernelGGL(k_sort16, dim3(BB), dim3(NN), 0, stream, e, order, dgrp, ntiles);
    hipLaunchKernelGGL(k_prep_wt, dim3(HH, ND), dim3(64), 0, stream, W0, WT0, F_IN, 64);
    hipLaunchKernelGGL(k_prep_wt, dim3(HH, ND), dim3(64), 0, stream, W1, WT1, HH, HH);

    hipLaunchKernelGGL(k_gather1, dim3(BB * TPB), dim3(512), 0, stream,
                       a, e, order, ntiles, bufB);
    hipLaunchKernelGGL((k_gemm<8>), dim3(BB * TPB), dim3(512), 0, stream,
                       bufB, (const unsigned short*)nullptr, WT0, b0, order, dgrp, ntiles, bufA);
    hipLaunchKernelGGL(k_pool_bf, dim3(TOTAL / 16), dim3(256), 0, stream, bufA, e, bufB);
    hipLaunchKernelGGL(k_gather2, dim3(BB * 20), dim3(512), 0, stream,
                       bufB, e, order, ntiles, bufA, S2p);
    hipLaunchKernelGGL((k_gemm<16>), dim3(BB * TPB), dim3(512), 0, stream,
                       bufA, S2p, WT1, b1, order, dgrp, ntiles, bufB);
    hipLaunchKernelGGL(k_pool_sum_part, dim3(BB * 32), dim3(256), 0, stream, bufB, e, partial);
    hipLaunchKernelGGL(k_sum_final, dim3(BB * HH / 256), dim3(256), 0, stream, partial, out);
}